// Round 7
// baseline (66.987 us; speedup 1.0000x reference)
//
#include <hip/hip_runtime.h>

#define N_IN   16384
#define N_OUT  16384
#define NE     300000
#define SEGS   8           // segments per gather block
#define STW    528         // u16 per-b stage stride (512 + 16 pad)
#define WBUF   (2 * STW)   // u16 per stage buffer per wave (2 b's)
#define SROW   256         // u16 per S_lds row (unpadded)

typedef unsigned int   u32;
typedef unsigned short u16;
typedef __attribute__((ext_vector_type(4))) float f32x4;
typedef __attribute__((ext_vector_type(2))) float f32x2;
typedef __attribute__((ext_vector_type(8))) short bf16x8;

// round-to-nearest-even fp32 -> bf16 bits
__device__ __forceinline__ u16 f2bf(float x) {
    union { float f; u32 u; } v; v.f = x;
    u32 r = v.u + 0x7fffu + ((v.u >> 16) & 1u);
    return (u16)(r >> 16);
}

// ---------------------------------------------------------------------------
// Kernel A: transpose features (128, N_IN) fp32 -> ftb[N_IN][128] bf16
// ---------------------------------------------------------------------------
__global__ void k_transpose(const float* __restrict__ feat, u16* __restrict__ ftb) {
    __shared__ float tile[32][33];
    int n0 = blockIdx.x * 32, c0 = blockIdx.y * 32;
    int tx = threadIdx.x, ty = threadIdx.y;
#pragma unroll
    for (int k = 0; k < 4; ++k)
        tile[ty + k * 8][tx] = feat[(size_t)(c0 + ty + k * 8) * N_IN + n0 + tx];
    __syncthreads();
#pragma unroll
    for (int k = 0; k < 4; ++k)
        ftb[(size_t)(n0 + ty + k * 8) * 128 + c0 + tx] = f2bf(tile[tx][ty + k * 8]);
}

// ---------------------------------------------------------------------------
// Kernel B: segment offsets (binary search) + proj B-fragments, merged
// ---------------------------------------------------------------------------
__global__ void k_setup(const int2* __restrict__ ei, const float* __restrict__ W5,
                        int* __restrict__ segoff, u16* __restrict__ Bfrag) {
    int g = blockIdx.x * 256 + threadIdx.x;
    if (g <= N_OUT) {
        if (g == N_OUT) segoff[g] = NE;
        else {
            int lo = 0, hi = NE;
            while (lo < hi) { int m = (lo + hi) >> 1; if (ei[m].x < g) lo = m + 1; else hi = m; }
            segoff[g] = lo;
        }
    }
    if (g < 4096) {
        int ks = g >> 9, rem = g & 511, l = rem >> 3, e = rem & 7;
        int k = ks * 32 + ((l >> 4) << 3) + e;
        int o = l & 15;
        Bfrag[g] = f2bf(W5[(k >> 4) * 256 + ((k & 15) << 4) + o]);
    }
}

// ---------------------------------------------------------------------------
// Kernel C: per-edge MLP, 4 edges per thread.
// hT[j][e] = bf16( w_e * h_e[j] )  (transposed, coalesced stores)
// ---------------------------------------------------------------------------
__global__ __launch_bounds__(256) void k_mlp(
        const float* __restrict__ pin, const float* __restrict__ pout,
        const float* __restrict__ wts, const int2* __restrict__ ei,
        const float* __restrict__ W0, const float* __restrict__ W1,
        const float* __restrict__ W2, const float* __restrict__ W3,
        const float* __restrict__ W4, u16* __restrict__ hT) {
    __shared__ float w0t[32];
    __shared__ float wt[4][256];   // wt[L][j*16 + i] = W(L+1)[i*16 + j]
    int tid = threadIdx.x;
    {
        int i = tid >> 4, jj = tid & 15;
        if (tid < 32) w0t[(tid & 15) * 2 + (tid >> 4)] = W0[tid];
        wt[0][jj * 16 + i] = W1[tid];
        wt[1][jj * 16 + i] = W2[tid];
        wt[2][jj * 16 + i] = W3[tid];
        wt[3][jj * 16 + i] = W4[tid];
    }
    __syncthreads();
    int ebase = (blockIdx.x * 256 + tid) * 4;
    if (ebase >= NE) return;   // NE%4==0 -> all-or-nothing per thread

    const int4* eip = (const int4*)(ei + ebase);
    int4 q01 = eip[0], q23 = eip[1];
    int io_[4] = {q01.x, q01.z, q23.x, q23.z};
    int ii_[4] = {q01.y, q01.w, q23.y, q23.w};

    float x[4], y[4];
#pragma unroll
    for (int ed = 0; ed < 4; ++ed) {
        float2 po = ((const float2*)pout)[io_[ed]];
        float2 pi = ((const float2*)pin)[ii_[ed]];
        x[ed] = po.x - pi.x; y[ed] = po.y - pi.y;
    }

    f32x2 h2[4][8];
#pragma unroll
    for (int q = 0; q < 8; ++q) {
        float wa0 = w0t[4 * q],     wb0 = w0t[4 * q + 1];
        float wa1 = w0t[4 * q + 2], wb1 = w0t[4 * q + 3];
#pragma unroll
        for (int ed = 0; ed < 4; ++ed)
            h2[ed][q] = (f32x2){__sinf(x[ed] * wa0 + y[ed] * wb0),
                                __sinf(x[ed] * wa1 + y[ed] * wb1)};
    }

#pragma unroll
    for (int L = 0; L < 4; ++L) {
        f32x2 nh2[4][8];
#pragma unroll
        for (int jj = 0; jj < 16; ++jj) {
            const f32x2* wr = (const f32x2*)&wt[L][jj * 16];
            f32x2 wv[8];
#pragma unroll
            for (int q = 0; q < 8; ++q) wv[q] = wr[q];
#pragma unroll
            for (int ed = 0; ed < 4; ++ed) {
                f32x2 acc = h2[ed][0] * wv[0];
#pragma unroll
                for (int q = 1; q < 8; ++q)
                    acc = __builtin_elementwise_fma(h2[ed][q], wv[q], acc);
                float hv = __sinf(acc.x + acc.y);
                if (jj & 1) nh2[ed][jj >> 1].y = hv; else nh2[ed][jj >> 1].x = hv;
            }
        }
#pragma unroll
        for (int ed = 0; ed < 4; ++ed)
#pragma unroll
            for (int q = 0; q < 8; ++q) h2[ed][q] = nh2[ed][q];
    }

    float we[4];
#pragma unroll
    for (int ed = 0; ed < 4; ++ed) we[ed] = wts[ii_[ed]];
#pragma unroll
    for (int jj = 0; jj < 16; ++jj) {
        int q = jj >> 1;
        float v0 = (jj & 1) ? h2[0][q].y : h2[0][q].x;
        float v1 = (jj & 1) ? h2[1][q].y : h2[1][q].x;
        float v2 = (jj & 1) ? h2[2][q].y : h2[2][q].x;
        float v3 = (jj & 1) ? h2[3][q].y : h2[3][q].x;
        u32 lo = (u32)f2bf(we[0] * v0) | ((u32)f2bf(we[1] * v1) << 16);
        u32 hi = (u32)f2bf(we[2] * v2) | ((u32)f2bf(we[3] * v3) << 16);
        *(uint2*)(hT + (size_t)jj * NE + ebase) = make_uint2(lo, hi);
    }
}

// ---------------------------------------------------------------------------
// Kernel D: fused MFMA gather + projection, BARRIER-FREE.
// 4 waves/block, each wave fully independent: owns 2 b's, has private stA
// double-buffer + private S_lds rows + register segment bounds (shfl).
// DS ops are in program order per wave -> no __syncthreads anywhere.
// ---------------------------------------------------------------------------
#define EIW(IA, IB, BSE) do {                                             \
    int g_ = (BSE) + 2 * pr; g_ = g_ <= NE - 2 ? g_ : NE - 2;             \
    int4 q_ = *(const int4*)(ei + g_); IA = q_.y; IB = q_.w; } while (0)

#define FTW(FA, FB, IA, IB) do {                                          \
    FA = ftb4[(size_t)(u32)(IA) * 16 + oct];                              \
    FB = ftb4[(size_t)(u32)(IB) * 16 + oct]; } while (0)

#define BQW(BQ, BSE) do {                                                 \
    int bb_ = (BSE); bb_ = bb_ <= NE - 32 ? bb_ : NE - 32;                \
    BQ = *(const bf16x8*)(hT + (size_t)j * NE + bb_ + kg * 8); } while (0)

#define STGW(DST, FA, FB) do {                                            \
    u32 aw_[4] = {FA.x, FA.y, FA.z, FA.w};                                \
    u32 bw_[4] = {FB.x, FB.y, FB.z, FB.w};                                \
    int wb_ = bloc * STW + (pr >> 2) * 128 + 2 * (pr & 3);                \
    _Pragma("unroll")                                                     \
    for (int m_ = 0; m_ < 8; ++m_) {                                      \
        u32 lo_ = (m_ & 1) ? (aw_[m_ >> 1] >> 16) : (aw_[m_ >> 1] & 0xffffu);      \
        u32 hi_ = (m_ & 1) ? (bw_[m_ >> 1] & 0xffff0000u) : (bw_[m_ >> 1] << 16);  \
        *(u32*)&(DST)[wb_ + (ibase + m_) * 8] = lo_ | hi_;                \
    } } while (0)

#define PIECE(KLO, KHI, BQ) do {                                          \
    bf16x8 bm_;                                                           \
    if ((KLO) == 0 && (KHI) == 32) { bm_ = BQ; }                          \
    else {                                                                \
        _Pragma("unroll")                                                 \
        for (int e_ = 0; e_ < 8; ++e_) {                                  \
            int k_ = kg * 8 + e_;                                         \
            bm_[e_] = (k_ >= (KLO) && k_ < (KHI)) ? BQ[e_] : (short)0;    \
        }                                                                 \
    }                                                                     \
    acc0 = __builtin_amdgcn_mfma_f32_16x16x32_bf16(a0, bm_, acc0, 0, 0, 0); \
    acc1 = __builtin_amdgcn_mfma_f32_16x16x32_bf16(a1, bm_, acc1, 0, 0, 0); \
} while (0)

#define DUMP() do {                                                       \
    u32 l0_ = (u32)f2bf(acc0[0]) | ((u32)f2bf(acc0[1]) << 16);            \
    u32 l1_ = (u32)f2bf(acc0[2]) | ((u32)f2bf(acc0[3]) << 16);            \
    *(uint2*)&S_lds[(b0 * SEGS + s) * SROW + j * 16 + kg * 4] = make_uint2(l0_, l1_); \
    u32 l2_ = (u32)f2bf(acc1[0]) | ((u32)f2bf(acc1[1]) << 16);            \
    u32 l3_ = (u32)f2bf(acc1[2]) | ((u32)f2bf(acc1[3]) << 16);            \
    *(uint2*)&S_lds[((b0 + 1) * SEGS + s) * SROW + j * 16 + kg * 4] = make_uint2(l2_, l3_); \
    acc0 = (f32x4){0.f, 0.f, 0.f, 0.f}; acc1 = (f32x4){0.f, 0.f, 0.f, 0.f}; \
} while (0)

__global__ __launch_bounds__(256, 3) void k_gather(
        const int2* __restrict__ ei, const u16* __restrict__ ftb,
        const u16* __restrict__ hT, const int* __restrict__ segoff,
        const u16* __restrict__ Bfrag, float* __restrict__ out)
{
    __shared__ __align__(16) u16 stA[4 * 2 * WBUF];      // 16,896 B
    __shared__ __align__(16) u16 S_lds[8 * SEGS * SROW]; // 32,768 B

    int tid = threadIdx.x, lane = tid & 63, wave = tid >> 6;
    int s0 = blockIdx.x * SEGS;
    int b0 = wave * 2;

    // segment bounds in registers, broadcast via shfl (no LDS, no barrier)
    int segv = segoff[s0 + (lane <= SEGS ? lane : SEGS)];
    int e0 = __shfl(segv, 0), e1 = __shfl(segv, SEGS);

    // roles
    int pr = lane >> 2, c4 = lane & 3;          // staging: edge-pair, oct
    int bloc = c4 >> 1, ibase = (c4 & 1) * 8;
    int oct = b0 * 2 + c4;                      // global ftb oct for this lane
    int j = lane & 15, kg = lane >> 4;          // B-frag / C-frag roles

    u16* stW = stA + wave * 2 * WBUF;           // private double buffer
    const uint4* ftb4 = (const uint4*)ftb;

    int base0 = e0 & ~31;                       // absolute 32-edge grid
    int nc = (e1 - base0 + 31) >> 5;

    f32x4 acc0 = {0.f, 0.f, 0.f, 0.f}, acc1 = {0.f, 0.f, 0.f, 0.f};

    if (nc > 0) {
        int eiA, eiB, eiA2, eiB2;
        uint4 gA, gB;
        bf16x8 bqC, bqN, bqL;
        EIW(eiA, eiB, base0);
        FTW(gA, gB, eiA, eiB);
        BQW(bqC, base0);
        EIW(eiA, eiB, base0 + 32);
        STGW(stW, gA, gB);                       // chunk 0 -> buf 0
        FTW(gA, gB, eiA, eiB);                   // chunk 1 in flight
        BQW(bqN, base0 + 32);
        EIW(eiA, eiB, base0 + 64);               // idx chunk 2

        int s = 0;
        for (int c = 0; c < nc; ++c) {
            int base = base0 + 32 * c;
            u16* rb = stW + (c & 1) * WBUF;
            bf16x8 a0 = *(const bf16x8*)&rb[lane * 8];
            bf16x8 a1 = *(const bf16x8*)&rb[STW + lane * 8];

            if (c + 1 < nc) {
                STGW(stW + ((c + 1) & 1) * WBUF, gA, gB);  // stage chunk c+1
                FTW(gA, gB, eiA, eiB);                     // chunk c+2 in flight
                BQW(bqL, base + 64);
                EIW(eiA2, eiB2, base + 96);
            }

            int ce = base + 32;
            int k_lo = (c == 0) ? (e0 - base0) : 0;
            int nxt = __shfl(segv, s + 1 <= SEGS ? s + 1 : SEGS);
            while (s < SEGS && nxt <= ce) {
                int k_hi = nxt - base;
                if (k_hi > k_lo) PIECE(k_lo, k_hi, bqC);
                DUMP();
                ++s; k_lo = k_hi;
                nxt = __shfl(segv, s + 1 <= SEGS ? s + 1 : SEGS);
            }
            if (s < SEGS && k_lo < 32) PIECE(k_lo, 32, bqC);

            bqC = bqN; bqN = bqL;
            eiA = eiA2; eiB = eiB2;
        }
    } else {
        // empty window: zero this wave's private S rows
        u32* zz = (u32*)&S_lds[b0 * SEGS * SROW];
        for (int I = lane; I < SEGS * SROW / 2; I += 64) zz[I] = 0;
    }

    // ---- projection epilogue (wave-local rows only, still no barrier) ----
    bf16x8 bfr[8];
#pragma unroll
    for (int ks = 0; ks < 8; ++ks)
        bfr[ks] = *(const bf16x8*)(Bfrag + ks * 512 + lane * 8);

#pragma unroll
    for (int bb = 0; bb < 2; ++bb) {
        int b = b0 + bb;
        f32x4 ap = {0.f, 0.f, 0.f, 0.f};
#pragma unroll
        for (int ks = 0; ks < 8; ++ks) {
            bf16x8 af = *(const bf16x8*)
                &S_lds[(b * SEGS + (lane & 7)) * SROW + ks * 32 + kg * 8];
            ap = __builtin_amdgcn_mfma_f32_16x16x32_bf16(af, bfr[ks], ap, 0, 0, 0);
        }
        int o = lane & 15;
        if (kg < 2)   // rows 0..7 valid (SEGS=8); rows 8..15 duplicates
            *(float4*)(out + (((size_t)(b * 16 + o)) << 14) + s0 + kg * 4) =
                make_float4(ap[0], ap[1], ap[2], ap[3]);
    }
}

// ---------------------------------------------------------------------------
extern "C" void kernel_launch(void* const* d_in, const int* in_sizes, int n_in,
                              void* d_out, int out_size, void* d_ws, size_t ws_size,
                              hipStream_t stream) {
    const float* pin  = (const float*)d_in[0];
    const float* pout = (const float*)d_in[1];
    const float* wts  = (const float*)d_in[2];
    const float* feat = (const float*)d_in[3];
    const int2*  ei   = (const int2*)d_in[4];
    const float* W0   = (const float*)d_in[5];
    const float* W1   = (const float*)d_in[6];
    const float* W2   = (const float*)d_in[7];
    const float* W3   = (const float*)d_in[8];
    const float* W4   = (const float*)d_in[9];
    const float* W5   = (const float*)d_in[10];
    float* out = (float*)d_out;

    u16* ftb    = (u16*)d_ws;                             // 4,194,304 B
    u16* hT     = ftb + (size_t)N_IN * 128;               // 9,600,000 B + pad
    int* segoff = (int*)(hT + (size_t)16 * NE + 64);      // 65,552 B
    u16* Bfrag  = (u16*)(segoff + 16388);                 // 8,192 B

    k_transpose<<<dim3(N_IN / 32, 4), dim3(32, 8), 0, stream>>>(feat, ftb);
    k_setup<<<(N_OUT + 256) / 256, 256, 0, stream>>>(ei, W5, segoff, Bfrag);
    k_mlp<<<(NE + 1023) / 1024, 256, 0, stream>>>(pin, pout, wts, ei,
                                                  W0, W1, W2, W3, W4, hT);
    k_gather<<<N_OUT / SEGS, 256, 0, stream>>>(ei, ftb, hT, segoff, Bfrag, out);
}